// Round 3
// 40254.617 us; speedup vs baseline: 1.6344x; 1.6344x over previous
//
#include <hip/hip_runtime.h>

// SimpleGRU R6: R3's proven primitives only, restructured to cut rounds.
// - x pre-split once to bf16 hi/lo (xs, in workspace; 130 MB total = R3 envelope).
// - Layer 0 phase A: x-part consumed as per-lane REGISTER fragments (plain
//   cached loads; xs is read-only during layer 0) -> 4 rounds only (h-part),
//   with x-MFMAs overlapping the h GLL latency. No in-loop conversion.
// - 12-slot WX weights (r,z,h cols; lanes 12-15 broadcast slots 8-11) fold
//   x@Wh into phase A's accumulator; carried in registers across the grid
//   barrier so phase B is rh-only (4 rounds).
// - Layer-1 input = h written IN-PLACE into xs (deferred one step; distinct
//   rows, race-free), flushed with one __threadfence; layer 1 stages x via
//   GLL bypass (aux 0x11) since reader L2s hold stale layer-0 x lines.
// - h/rh per-step exchange: unchanged R3 mechanism (bypass GLL + bypass
//   stores, relaxed-atomic two-level grid barrier). No asm loads, no
//   hand-counted vmcnt anywhere.

#define TPB 256
#define NBLK 256
#define B_ 64
#define S_ 512
#define H_ 1024
#define KTOT 2048
#define NROW 32768   // B_*S_ rows per layer

typedef float f32x4 __attribute__((ext_vector_type(4)));
typedef short short8 __attribute__((ext_vector_type(8)));

// LDS layout (units: shorts). Total 81920 shorts = 160 KiB exactly.
#define WX_HI  0        // 12288: x-rows, 128 k-octets x 12 slots (r,z,h)
#define WX_LO  12288
#define WRZ_HI 24576    // 8192: h-rows of Wr|Wz, 128 k-octets x 8 slots
#define WRZ_LO 32768
#define WN_HI  40960    // 4096: rh-rows of Wh, 128 k-octets x 4 slots
#define WN_LO  45056
#define A_HI   49152    // 16384: staged A chunk (64 rows x 256 K), hi
#define A_LO   65536    // 16384: lo
#define LDS_SHORTS 81920

#define MFMA16 __builtin_amdgcn_mfma_f32_16x16x32_bf16

// bypass (sc0|sc1): always-coherent LLC path (h/rh pubs, layer-1 xs)
#define GLL(gp, lp) \
    __builtin_amdgcn_global_load_lds((__attribute__((address_space(1))) const void*)(const void*)(gp), \
                                     (__attribute__((address_space(3))) void*)(void*)(lp), 16, 0, 0x11)

__device__ __forceinline__ unsigned short f2bf(float f) {
    unsigned u = __float_as_uint(f);
    u += 0x7fffu + ((u >> 16) & 1u);
    return (unsigned short)(u >> 16);
}
__device__ __forceinline__ float bf2f(unsigned short s) {
    return __uint_as_float(((unsigned)s) << 16);
}
__device__ __forceinline__ float sigm(float v) { return 1.0f / (1.0f + expf(-v)); }

__device__ __forceinline__ void store_short_bypass(const unsigned short* addr, unsigned short v) {
    asm volatile("global_store_short %0, %1, off sc0 sc1"
                 :: "v"((unsigned long long)(uintptr_t)addr), "v"((unsigned)v) : "memory");
}
__device__ __forceinline__ void waitcnt0() {
    asm volatile("s_waitcnt vmcnt(0)" ::: "memory");
}

// Two-level grid barrier, RELAXED atomics only (no cache maintenance).
__device__ __forceinline__ void gbar(unsigned* bar, int grp) {
    __syncthreads();   // drains each wave's vmcnt (incl. bypass stores) before arrival
    if (threadIdx.x == 0) {
        unsigned* cnt  = bar + grp * 32;
        unsigned* gen  = bar + 256 + grp * 32;
        unsigned* ccnt = bar + 512;
        unsigned g = __hip_atomic_load(gen, __ATOMIC_RELAXED, __HIP_MEMORY_SCOPE_AGENT);
        if (__hip_atomic_fetch_add(cnt, 1u, __ATOMIC_RELAXED, __HIP_MEMORY_SCOPE_AGENT) == 31u) {
            __hip_atomic_store(cnt, 0u, __ATOMIC_RELAXED, __HIP_MEMORY_SCOPE_AGENT);
            waitcnt0();
            if (__hip_atomic_fetch_add(ccnt, 1u, __ATOMIC_RELAXED, __HIP_MEMORY_SCOPE_AGENT) == 7u) {
                __hip_atomic_store(ccnt, 0u, __ATOMIC_RELAXED, __HIP_MEMORY_SCOPE_AGENT);
                waitcnt0();
                #pragma unroll
                for (int i = 0; i < 8; ++i)
                    __hip_atomic_store(bar + 256 + i * 32, g + 1u,
                                       __ATOMIC_RELAXED, __HIP_MEMORY_SCOPE_AGENT);
            } else {
                while (__hip_atomic_load(gen, __ATOMIC_RELAXED, __HIP_MEMORY_SCOPE_AGENT) == g)
                    __builtin_amdgcn_s_sleep(8);
            }
        } else {
            while (__hip_atomic_load(gen, __ATOMIC_RELAXED, __HIP_MEMORY_SCOPE_AGENT) == g)
                __builtin_amdgcn_s_sleep(8);
        }
    }
    __syncthreads();
}

__global__ __launch_bounds__(TPB, 1) void gru_fk(
    const float* __restrict__ x,    // [64][512][1024]  row = m*512 + t
    const float* __restrict__ Wr,   // [2][2048][1024]
    const float* __restrict__ Wz,
    const float* __restrict__ Wh,
    const float* __restrict__ pbr,  // [2][1024]
    const float* __restrict__ pbz,
    const float* __restrict__ pbh,
    float* __restrict__ out,        // [64][512][1024]
    unsigned short* __restrict__ h_hi,   // [64][1024] bf16 (bypass-only)
    unsigned short* __restrict__ h_lo,
    unsigned short* __restrict__ rh_hi,
    unsigned short* __restrict__ rh_lo,
    float* __restrict__ hpriv,      // [256 blk][64][4]  (block-private)
    float* __restrict__ zpriv,
    unsigned short* __restrict__ xs_hi,  // [32768][1024] split input (in-place rewrite for layer 1)
    unsigned short* __restrict__ xs_lo,
    unsigned* __restrict__ bar)
{
    __shared__ short lds[LDS_SHORTS];
    const int lane = threadIdx.x & 63;
    const int wave = threadIdx.x >> 6;
    const int c0   = blockIdx.x << 2;          // 4 output cols per block
    const int grp  = blockIdx.x & 7;
    float* hp = hpriv + (blockIdx.x << 8);
    float* zp = zpriv + (blockIdx.x << 8);

    const int q    = lane >> 4;                  // k-octet / C row-group
    const int jc   = lane & 15;                  // C/D col slot & A row-in-tile
    const int jcs  = (jc < 12) ? jc : jc - 4;    // WX slot (12-15 broadcast 8-11)
    const int mrow = wave * 16 + jc;             // batch row this lane loads A for
    const int oct  = q << 3;                     // k offset of lane's octet

    for (int l = 0; l < 2; ++l) {
        // ---- layer-0 only: pre-split x -> (hi, lo) bf16, linear ----
        if (l == 0) {
            for (int i = threadIdx.x + blockIdx.x * TPB; i < NROW * H_ / 8; i += TPB * NBLK) {
                const float* src = x + (size_t)i * 8;
                float4 v0 = *(const float4*)src;
                float4 v1 = *(const float4*)(src + 4);
                float vv[8] = {v0.x, v0.y, v0.z, v0.w, v1.x, v1.y, v1.z, v1.w};
                short8 hi, lo;
                #pragma unroll
                for (int j = 0; j < 8; ++j) {
                    unsigned short hb = f2bf(vv[j]);
                    hi[j] = (short)hb; lo[j] = (short)f2bf(vv[j] - bf2f(hb));
                }
                *(short8*)&xs_hi[(size_t)i * 8] = hi;
                *(short8*)&xs_lo[(size_t)i * 8] = lo;
            }
            __threadfence();   // flush converted x to LLC for all readers
            waitcnt0();
        }
        gbar(bar, grp);   // l=0: xs ready; l=1: in-place rewrite flushed

        // ---- stage weights ----
        // WX: x-rows (k 0..1023), 12 slots: r0-3, z0-3, h0-3
        for (int g = threadIdx.x; g < 1536; g += TPB) {
            int n = g % 12, ko = g / 12;
            int k = ko * 8;
            int col = c0 + (n & 3);
            int gate = n >> 2;                   // 0=r, 1=z, 2=h
            const float* Wg = (gate == 0) ? Wr : (gate == 1) ? Wz : Wh;
            short8 hi, lo;
            #pragma unroll
            for (int j = 0; j < 8; ++j) {
                float v = Wg[((size_t)(l * KTOT + k + j)) * H_ + col];
                unsigned short hb = f2bf(v);
                hi[j] = (short)hb; lo[j] = (short)f2bf(v - bf2f(hb));
            }
            *(short8*)&lds[WX_HI + g * 8] = hi;
            *(short8*)&lds[WX_LO + g * 8] = lo;
        }
        // WRZ: h-rows (k 1024..2047) of Wr,Wz — 8 slots (lanes 8-15 broadcast)
        for (int g = threadIdx.x; g < 1024; g += TPB) {
            int n = g & 7, ko = g >> 3;
            int k = 1024 + ko * 8;
            int col = c0 + (n & 3);
            const float* Wg = (n < 4) ? Wr : Wz;
            short8 hi, lo;
            #pragma unroll
            for (int j = 0; j < 8; ++j) {
                float v = Wg[((size_t)(l * KTOT + k + j)) * H_ + col];
                unsigned short hb = f2bf(v);
                hi[j] = (short)hb; lo[j] = (short)f2bf(v - bf2f(hb));
            }
            *(short8*)&lds[WRZ_HI + g * 8] = hi;
            *(short8*)&lds[WRZ_LO + g * 8] = lo;
        }
        // WN: rh-rows (k 1024..2047) of Wh — 4 slots (lanes broadcast via &3)
        for (int g = threadIdx.x; g < 512; g += TPB) {
            int n = g & 3, ko = g >> 2;
            int k = 1024 + ko * 8;
            int col = c0 + n;
            short8 hi, lo;
            #pragma unroll
            for (int j = 0; j < 8; ++j) {
                float v = Wh[((size_t)(l * KTOT + k + j)) * H_ + col];
                unsigned short hb = f2bf(v);
                hi[j] = (short)hb; lo[j] = (short)f2bf(v - bf2f(hb));
            }
            *(short8*)&lds[WN_HI + g * 8] = hi;
            *(short8*)&lds[WN_LO + g * 8] = lo;
        }
        // ---- init h = 0 (private + published) ----
        {
            int m = threadIdx.x & 63, cc = threadIdx.x >> 6;
            hp[(m << 2) | cc] = 0.0f;
            store_short_bypass(h_hi + m * H_ + c0 + cc, 0);
            store_short_bypass(h_lo + m * H_ + c0 + cc, 0);
        }
        gbar(bar, grp);

        const float brv = pbr[l * H_ + c0 + (jc & 3)];
        const float bzv = pbz[l * H_ + c0 + (jc & 3)];
        const float bhv = pbh[l * H_ + c0 + (jc & 3)];

        for (int t = 0; t < S_; ++t) {
            const size_t xrow = ((size_t)(mrow * S_ + t)) * H_ + oct;
            f32x4 accX = {0.f, 0.f, 0.f, 0.f};   // slots: r(0-3), z(4-7), x@Wh(8-11)
            f32x4 accH = {0.f, 0.f, 0.f, 0.f};   // slots: r(0-3), z(4-7) recurrent

            // =================== Phase A ===================
            if (l == 0) {
                // 4 rounds: issue h-chunk GLL, overlap with x register MFMAs
                for (int c = 0; c < 4; ++c) {
                    #pragma unroll
                    for (int i = 0; i < 8; ++i) {
                        int sg = wave * 8 + i;
                        int kc = sg >> 2, ms = sg & 3;
                        int m  = ms * 16 + (lane & 15);
                        int kh = c * 256 + kc * 32 + ((lane >> 4) << 3);
                        GLL(h_hi + m * H_ + kh, &lds[A_HI + sg * 512]);
                        GLL(h_lo + m * H_ + kh, &lds[A_LO + sg * 512]);
                    }
                    // x-part from registers (plain cached loads; xs read-only here)
                    #pragma unroll
                    for (int kk = 0; kk < 8; ++kk) {
                        int ks = c * 8 + kk;
                        short8 ah  = *(const short8*)(xs_hi + xrow + ks * 32);
                        short8 al  = *(const short8*)(xs_lo + xrow + ks * 32);
                        short8 bh_ = *(short8*)&lds[WX_HI + ((ks * 4 + q) * 12 + jcs) * 8];
                        short8 bl_ = *(short8*)&lds[WX_LO + ((ks * 4 + q) * 12 + jcs) * 8];
                        accX = MFMA16(ah, bh_, accX, 0, 0, 0);
                        accX = MFMA16(al, bh_, accX, 0, 0, 0);
                        accX = MFMA16(ah, bl_, accX, 0, 0, 0);
                    }
                    __syncthreads();
                    #pragma unroll
                    for (int kk = 0; kk < 8; ++kk) {
                        int kg = c * 8 + kk;
                        short8 bh_ = *(short8*)&lds[WRZ_HI + ((kg * 4 + q) * 8 + (lane & 7)) * 8];
                        short8 bl_ = *(short8*)&lds[WRZ_LO + ((kg * 4 + q) * 8 + (lane & 7)) * 8];
                        short8 ah  = *(short8*)&lds[A_HI + ((kk * 4 + wave) * 64 + lane) * 8];
                        short8 al  = *(short8*)&lds[A_LO + ((kk * 4 + wave) * 64 + lane) * 8];
                        accH = MFMA16(ah, bh_, accH, 0, 0, 0);
                        accH = MFMA16(al, bh_, accH, 0, 0, 0);
                        accH = MFMA16(ah, bl_, accH, 0, 0, 0);
                    }
                    __syncthreads();
                }
            } else {
                // layer 1: xs was rewritten in place -> reader L2s stale ->
                // stage x via bypass GLL (4 rounds), then h (4 rounds)
                for (int c = 0; c < 4; ++c) {
                    #pragma unroll
                    for (int i = 0; i < 8; ++i) {
                        int sg = wave * 8 + i;
                        int kc = sg >> 2, ms = sg & 3;
                        int m  = ms * 16 + (lane & 15);
                        int kx = c * 256 + kc * 32 + ((lane >> 4) << 3);
                        GLL(xs_hi + ((size_t)(m * S_ + t)) * H_ + kx, &lds[A_HI + sg * 512]);
                        GLL(xs_lo + ((size_t)(m * S_ + t)) * H_ + kx, &lds[A_LO + sg * 512]);
                    }
                    __syncthreads();
                    #pragma unroll
                    for (int kk = 0; kk < 8; ++kk) {
                        int ks = c * 8 + kk;
                        short8 bh_ = *(short8*)&lds[WX_HI + ((ks * 4 + q) * 12 + jcs) * 8];
                        short8 bl_ = *(short8*)&lds[WX_LO + ((ks * 4 + q) * 12 + jcs) * 8];
                        short8 ah  = *(short8*)&lds[A_HI + ((kk * 4 + wave) * 64 + lane) * 8];
                        short8 al  = *(short8*)&lds[A_LO + ((kk * 4 + wave) * 64 + lane) * 8];
                        accX = MFMA16(ah, bh_, accX, 0, 0, 0);
                        accX = MFMA16(al, bh_, accX, 0, 0, 0);
                        accX = MFMA16(ah, bl_, accX, 0, 0, 0);
                    }
                    __syncthreads();
                }
                for (int c = 0; c < 4; ++c) {
                    #pragma unroll
                    for (int i = 0; i < 8; ++i) {
                        int sg = wave * 8 + i;
                        int kc = sg >> 2, ms = sg & 3;
                        int m  = ms * 16 + (lane & 15);
                        int kh = c * 256 + kc * 32 + ((lane >> 4) << 3);
                        GLL(h_hi + m * H_ + kh, &lds[A_HI + sg * 512]);
                        GLL(h_lo + m * H_ + kh, &lds[A_LO + sg * 512]);
                    }
                    __syncthreads();
                    #pragma unroll
                    for (int kk = 0; kk < 8; ++kk) {
                        int kg = c * 8 + kk;
                        short8 bh_ = *(short8*)&lds[WRZ_HI + ((kg * 4 + q) * 8 + (lane & 7)) * 8];
                        short8 bl_ = *(short8*)&lds[WRZ_LO + ((kg * 4 + q) * 8 + (lane & 7)) * 8];
                        short8 ah  = *(short8*)&lds[A_HI + ((kk * 4 + wave) * 64 + lane) * 8];
                        short8 al  = *(short8*)&lds[A_LO + ((kk * 4 + wave) * 64 + lane) * 8];
                        accH = MFMA16(ah, bh_, accH, 0, 0, 0);
                        accH = MFMA16(al, bh_, accH, 0, 0, 0);
                        accH = MFMA16(ah, bl_, accH, 0, 0, 0);
                    }
                    __syncthreads();
                }
            }
            // epilogue A: r,z = sigmoid(x-part + h-part + bias)
            if (jc < 8) {
                const bool isr = jc < 4;
                const int cloc = jc & 3;
                const int col = c0 + cloc;
                const float bias = isr ? brv : bzv;
                #pragma unroll
                for (int i = 0; i < 4; ++i) {
                    int m = wave * 16 + q * 4 + i;
                    float gt = sigm(accX[i] + accH[i] + bias);
                    if (isr) {
                        float rh = gt * hp[(m << 2) | cloc];
                        unsigned short hb2 = f2bf(rh);
                        store_short_bypass(rh_hi + m * H_ + col, hb2);
                        store_short_bypass(rh_lo + m * H_ + col, f2bf(rh - bf2f(hb2)));
                    } else {
                        zp[(m << 2) | cloc] = gt;
                    }
                }
            } else if (l == 0 && jc >= 12 && t > 0) {
                // deferred in-place write of layer-1 input row (t-1): hp still
                // holds h(t-1); all reads of xs row (t-1) ended 2 gbars ago.
                const int cl = jc - 12;
                #pragma unroll
                for (int i = 0; i < 4; ++i) {
                    int m = wave * 16 + q * 4 + i;
                    float hv = hp[(m << 2) | cl];
                    unsigned short hb2 = f2bf(hv);
                    size_t off = ((size_t)(m * S_ + (t - 1))) * H_ + c0 + cl;
                    xs_hi[off] = hb2;
                    xs_lo[off] = f2bf(hv - bf2f(hb2));
                }
            }
            gbar(bar, grp);

            // =================== Phase B: rh-part only ===================
            f32x4 acc2 = {0.f, 0.f, 0.f, 0.f};
            for (int c = 0; c < 4; ++c) {
                #pragma unroll
                for (int i = 0; i < 8; ++i) {
                    int sg = wave * 8 + i;
                    int kc = sg >> 2, ms = sg & 3;
                    int m  = ms * 16 + (lane & 15);
                    int kh = c * 256 + kc * 32 + ((lane >> 4) << 3);
                    GLL(rh_hi + m * H_ + kh, &lds[A_HI + sg * 512]);
                    GLL(rh_lo + m * H_ + kh, &lds[A_LO + sg * 512]);
                }
                __syncthreads();
                #pragma unroll
                for (int kk = 0; kk < 8; ++kk) {
                    int kg = c * 8 + kk;
                    short8 bh_ = *(short8*)&lds[WN_HI + ((kg * 4 + q) * 4 + (lane & 3)) * 8];
                    short8 bl_ = *(short8*)&lds[WN_LO + ((kg * 4 + q) * 4 + (lane & 3)) * 8];
                    short8 ah  = *(short8*)&lds[A_HI + ((kk * 4 + wave) * 64 + lane) * 8];
                    short8 al  = *(short8*)&lds[A_LO + ((kk * 4 + wave) * 64 + lane) * 8];
                    acc2 = MFMA16(ah, bh_, acc2, 0, 0, 0);
                    acc2 = MFMA16(al, bh_, acc2, 0, 0, 0);
                    acc2 = MFMA16(ah, bl_, acc2, 0, 0, 0);
                }
                __syncthreads();
            }
            // epilogue B: n = tanh(carried x@Wh + rh@Wh + bh); h update
            if (jc >= 8 && jc < 12) {
                const int cl = jc & 3;
                const int col = c0 + cl;
                #pragma unroll
                for (int i = 0; i < 4; ++i) {
                    int m = wave * 16 + q * 4 + i;
                    float nv = tanhf(accX[i] + acc2[i] + bhv);
                    float zz = zp[(m << 2) | cl];
                    float ho = hp[(m << 2) | cl];
                    float hn = (1.0f - zz) * nv + zz * ho;
                    hp[(m << 2) | cl] = hn;
                    unsigned short hb2 = f2bf(hn);
                    unsigned short lb2 = f2bf(hn - bf2f(hb2));
                    store_short_bypass(h_hi + m * H_ + col, hb2);
                    store_short_bypass(h_lo + m * H_ + col, lb2);
                    if (l == 1) out[((size_t)(m * S_ + t)) * H_ + col] = hn;
                }
            }
            gbar(bar, grp);
        }

        if (l == 0) {
            // final deferred row (t = 511), then flush in-place rewrite to LLC
            if (jc >= 12) {
                const int cl = jc - 12;
                #pragma unroll
                for (int i = 0; i < 4; ++i) {
                    int m = wave * 16 + q * 4 + i;
                    float hv = hp[(m << 2) | cl];
                    unsigned short hb2 = f2bf(hv);
                    size_t off = ((size_t)(m * S_ + 511)) * H_ + c0 + cl;
                    xs_hi[off] = hb2;
                    xs_lo[off] = f2bf(hv - bf2f(hb2));
                }
            }
            __threadfence();
            waitcnt0();
        }
    }
}

extern "C" void kernel_launch(void* const* d_in, const int* in_sizes, int n_in,
                              void* d_out, int out_size, void* d_ws, size_t ws_size,
                              hipStream_t stream) {
    const float* x  = (const float*)d_in[0];
    const float* Wr = (const float*)d_in[1];
    const float* Wz = (const float*)d_in[2];
    const float* Wh = (const float*)d_in[3];
    const float* br = (const float*)d_in[4];
    const float* bz = (const float*)d_in[5];
    const float* bh = (const float*)d_in[6];
    float* out = (float*)d_out;

    char* ws = (char*)d_ws;
    unsigned* bar        = (unsigned*)ws;                    // 4 KB
    unsigned short* h_hi = (unsigned short*)(ws + 4096);     // 128 KB each
    unsigned short* h_lo = (unsigned short*)(ws + 135168);
    unsigned short* rhhi = (unsigned short*)(ws + 266240);
    unsigned short* rhlo = (unsigned short*)(ws + 397312);
    float* hpriv         = (float*)(ws + 528384);            // 256 KB
    float* zpriv         = (float*)(ws + 790528);            // 256 KB
    unsigned short* xshi = (unsigned short*)(ws + (2ull  << 20));   // 64 MB
    unsigned short* xslo = (unsigned short*)(ws + (66ull << 20));   // 64 MB
    // total footprint: 130 MB (identical to the validated R3 envelope)

    hipMemsetAsync(d_ws, 0, 4096, stream);   // barrier state
    gru_fk<<<NBLK, TPB, 0, stream>>>(x, Wr, Wz, Wh, br, bz, bh, out,
                                     h_hi, h_lo, rhhi, rhlo, hpriv, zpriv,
                                     xshi, xslo, bar);
}